// Round 8
// baseline (83.918 us; speedup 1.0000x reference)
//
#include <hip/hip_runtime.h>
#include <hip/hip_bf16.h>

// MultiHeadAttention: B=4,S=2048,E=1024,H=16,D=64. Q=K=V=x@Wq^T (quirk),
// causal, scale 1/32 (sqrt(OUT_DIM) quirk). fp32 in/out, bf16 MFMA compute.
// ws: [0,16MiB) q bf16 [B,H,S,D]; [16MiB,32MiB) qT bf16 [B,H,D,S].

using bf16 = __hip_bfloat16;
typedef __attribute__((ext_vector_type(8))) short bf16x8;
typedef __attribute__((ext_vector_type(4))) float f32x4;
typedef __attribute__((ext_vector_type(16))) float f32x16;
typedef __attribute__((ext_vector_type(2))) unsigned int u32x2;

#define MFMA16(a, b, c) __builtin_amdgcn_mfma_f32_16x16x32_bf16((a), (b), (c), 0, 0, 0)
#define MFMA32(a, b, c) __builtin_amdgcn_mfma_f32_32x32x16_bf16((a), (b), (c), 0, 0, 0)

// hardware packed f32x2 -> bf16x2 (RNE), T12 recipe
static __device__ __forceinline__ unsigned cvtpk(float lo, float hi) {
  unsigned r;
  asm("v_cvt_pk_bf16_f32 %0, %1, %2" : "=v"(r) : "v"(lo), "v"(hi));
  return r;
}
// scale a bf16x8 fragment by s (unpack, mul, repack)
static __device__ __forceinline__ bf16x8 scale8(bf16x8 f, float s) {
  union { bf16x8 v; unsigned w[4]; } u, r;
  u.v = f;
#pragma unroll
  for (int i = 0; i < 4; ++i) {
    float lo = __uint_as_float(u.w[i] << 16) * s;
    float hi = __uint_as_float(u.w[i] & 0xffff0000u) * s;
    r.w[i] = cvtpk(lo, hi);
  }
  return r.v;
}

// ---------------------------------------------------------------------------
// Kernel 1: q = x @ Wq^T (M=8192,N=1024,K=1024). 128x128 tile, 4 waves, BK=32.
// r7 (unchanged): T14 double-buffered K-loop, hw cvtpk staging, LDS-transpose
// epilogue with odd-stride pad for coalesced qT stores.
// ---------------------------------------------------------------------------
__global__ __launch_bounds__(256, 2) void qproj_kernel(
    const float* __restrict__ x, const float* __restrict__ w,
    ushort* __restrict__ q, ushort* __restrict__ qT) {
  __shared__ union {
    struct { ushort As[2][128][40]; ushort Bs[2][128][40]; } ab;
    ushort Tt[128][138];  // [dh-local][s-local] transpose tile, 276B stride
  } sm;
  const int tid = threadIdx.x;
  const int wid = tid >> 6, lane = tid & 63;
  const int l16 = lane & 15, lhi = lane >> 4;
  const int wrow = wid >> 1, wcol = wid & 1;
  const int m0 = blockIdx.x * 128, n0 = blockIdx.y * 128;

  const int sre[4] = {((0 * 256 + tid) * 4) >> 5, ((1 * 256 + tid) * 4) >> 5,
                      ((2 * 256 + tid) * 4) >> 5, ((3 * 256 + tid) * 4) >> 5};
  const int sce = (tid * 4) & 31;

  f32x4 acc[4][4] = {};
  float4 xa[4], wb[4];

#pragma unroll
  for (int i = 0; i < 4; ++i) {
    xa[i] = *reinterpret_cast<const float4*>(&x[(m0 + sre[i]) * 1024 + sce]);
    wb[i] = *reinterpret_cast<const float4*>(&w[(n0 + sre[i]) * 1024 + sce]);
  }
#pragma unroll
  for (int i = 0; i < 4; ++i) {
    uint2 pa = {cvtpk(xa[i].x, xa[i].y), cvtpk(xa[i].z, xa[i].w)};
    uint2 pb = {cvtpk(wb[i].x, wb[i].y), cvtpk(wb[i].z, wb[i].w)};
    *reinterpret_cast<uint2*>(&sm.ab.As[0][sre[i]][sce]) = pa;
    *reinterpret_cast<uint2*>(&sm.ab.Bs[0][sre[i]][sce]) = pb;
  }
  __syncthreads();

  for (int k0 = 0; k0 < 1024; k0 += 32) {
    const int p = (k0 >> 5) & 1;
    const bool more = (k0 + 32 < 1024);
    if (more) {
#pragma unroll
      for (int i = 0; i < 4; ++i) {
        xa[i] = *reinterpret_cast<const float4*>(&x[(m0 + sre[i]) * 1024 + k0 + 32 + sce]);
        wb[i] = *reinterpret_cast<const float4*>(&w[(n0 + sre[i]) * 1024 + k0 + 32 + sce]);
      }
    }

    bf16x8 af[4], bfr[4];
#pragma unroll
    for (int mr = 0; mr < 4; ++mr)
      af[mr] = *reinterpret_cast<const bf16x8*>(&sm.ab.As[p][wrow * 64 + mr * 16 + l16][lhi * 8]);
#pragma unroll
    for (int nr = 0; nr < 4; ++nr)
      bfr[nr] = *reinterpret_cast<const bf16x8*>(&sm.ab.Bs[p][wcol * 64 + nr * 16 + l16][lhi * 8]);
    __builtin_amdgcn_s_setprio(1);
#pragma unroll
    for (int mr = 0; mr < 4; ++mr)
#pragma unroll
      for (int nr = 0; nr < 4; ++nr)
        acc[mr][nr] = MFMA16(af[mr], bfr[nr], acc[mr][nr]);
    __builtin_amdgcn_s_setprio(0);

    if (more) {
#pragma unroll
      for (int i = 0; i < 4; ++i) {
        uint2 pa = {cvtpk(xa[i].x, xa[i].y), cvtpk(xa[i].z, xa[i].w)};
        uint2 pb = {cvtpk(wb[i].x, wb[i].y), cvtpk(wb[i].z, wb[i].w)};
        *reinterpret_cast<uint2*>(&sm.ab.As[p ^ 1][sre[i]][sce]) = pa;
        *reinterpret_cast<uint2*>(&sm.ab.Bs[p ^ 1][sre[i]][sce]) = pb;
      }
      __syncthreads();
    }
  }

  __syncthreads();  // As/Bs dead; reuse LDS as transpose tile

#pragma unroll
  for (int mr = 0; mr < 4; ++mr)
#pragma unroll
    for (int nr = 0; nr < 4; ++nr) {
      unsigned w01 = cvtpk(acc[mr][nr][0], acc[mr][nr][1]);
      unsigned w23 = cvtpk(acc[mr][nr][2], acc[mr][nr][3]);
      int rloc = wrow * 64 + mr * 16 + lhi * 4;
      int cloc = wcol * 64 + nr * 16 + l16;
      int gr = m0 + rloc, gc = n0 + cloc;
      int bb = gr >> 11, hh = gc >> 6, dh = gc & 63;
      ushort* qp = &q[(((bb * 16 + hh) * 2048) + (gr & 2047)) * 64 + dh];
      qp[0] = (ushort)(w01 & 0xffffu);
      qp[64] = (ushort)(w01 >> 16);
      qp[128] = (ushort)(w23 & 0xffffu);
      qp[192] = (ushort)(w23 >> 16);
      *reinterpret_cast<unsigned*>(&sm.Tt[cloc][rloc]) = w01;
      *reinterpret_cast<unsigned*>(&sm.Tt[cloc][rloc + 2]) = w23;
    }
  __syncthreads();

  const int bb = m0 >> 11, sl = m0 & 2047;
#pragma unroll
  for (int pp = 0; pp < 2; ++pp) {
    int dh_loc = (tid >> 2) + pp * 64;
    int gc = n0 + dh_loc;
    int hh = gc >> 6, dh = gc & 63;
    ushort* base = &qT[(((bb * 16 + hh) * 64) + dh) * 2048 + sl];
#pragma unroll
    for (int k = 0; k < 4; ++k) {
      int sb = (tid & 3) * 8 + k * 32;
      bf16x8 v = *reinterpret_cast<const bf16x8*>(&sm.Tt[dh_loc][sb]);
      *reinterpret_cast<bf16x8*>(&base[sb]) = v;
    }
  }
}

// ---------------------------------------------------------------------------
// Kernel 2: causal flash attention, K=V=Q. Block = 4 waves x 32 q-rows (128).
// Swapped QK^T / swapped PV (r2 layouts), qt-pairing (r4), KVBLK=128 +
// fixed-m softmax (r5), pre-scaled Q + hw cvt_pk (r6). New (r8): intra-tile
// re-schedule — exp2 split around PV halves, staging ds_writes between the
// PV halves (drain under compute, cheap barrier), item-B Q-frag prefetch.
// ---------------------------------------------------------------------------
__global__ __launch_bounds__(256, 2) void attn_kernel(
    const ushort* __restrict__ q, const ushort* __restrict__ qT,
    float* __restrict__ out) {
  __shared__ ushort Ks[2][128][72];    // [buf][key][d]  144B stride: conflict-free
  __shared__ ushort VTs[2][64][136];   // [buf][d][key]  272B stride: conflict-free
  const int tid = threadIdx.x, wid = tid >> 6, lane = tid & 63;
  const int l31 = lane & 31, h = lane >> 5;
  const int bid = blockIdx.x;
  const int pi = bid >> 6, bh = bid & 63;
  const int qtA = pi, qtB = 15 - pi;   // 128-row q tiles
  const int ntA = pi + 1;              // 128-key tiles for item A
  const int T = 17;                    // ntA + ntB == 17 for every block
  const ushort* Q = q + bh * (2048 * 64);
  const ushort* VT = qT + bh * (64 * 2048);
  float* O = out + (bh >> 4) * (2048 * 1024) + (bh & 15) * 64;

  int qw = qtA * 128 + wid * 32;
  int qglob = qw + l31;

  const int krow = tid >> 3, kc8 = (tid & 7) * 8;    // K: 4 rows/thread (+32)
  const int vrow = tid >> 4, vc8 = (tid & 15) * 8;   // VT: 4 rows/thread (+16)

  const float sc = 0.03125f * 1.44269504f;  // 1/sqrt(1024) * log2(e)

  bf16x8 qb[4], qbB[4];
#pragma unroll
  for (int ds = 0; ds < 4; ++ds)
    qb[ds] = scale8(*reinterpret_cast<const bf16x8*>(&Q[qglob * 64 + ds * 16 + h * 8]), sc);

  f32x16 o0 = {}, o1 = {};             // O^T[d][q]
  float l_run = 0.f;

  auto store_out = [&]() {
    float lt = l_run + __shfl_xor(l_run, 32);
    float inv = 1.0f / lt;
#pragma unroll
    for (int rq = 0; rq < 4; ++rq) {
      float4 v0, v1;
      v0.x = o0[4 * rq + 0] * inv; v0.y = o0[4 * rq + 1] * inv;
      v0.z = o0[4 * rq + 2] * inv; v0.w = o0[4 * rq + 3] * inv;
      v1.x = o1[4 * rq + 0] * inv; v1.y = o1[4 * rq + 1] * inv;
      v1.z = o1[4 * rq + 2] * inv; v1.w = o1[4 * rq + 3] * inv;
      *reinterpret_cast<float4*>(&O[qglob * 1024 + 8 * rq + 4 * h]) = v0;
      *reinterpret_cast<float4*>(&O[qglob * 1024 + 32 + 8 * rq + 4 * h]) = v1;
    }
  };

  bf16x8 kr[4], vr[4];
  // prologue: stage tile kv=0 into buffer 0
#pragma unroll
  for (int i = 0; i < 4; ++i) {
    kr[i] = *reinterpret_cast<const bf16x8*>(&Q[(krow + 32 * i) * 64 + kc8]);
    vr[i] = *reinterpret_cast<const bf16x8*>(&VT[(vrow + 16 * i) * 2048 + vc8]);
    *reinterpret_cast<bf16x8*>(&Ks[0][krow + 32 * i][kc8]) = kr[i];
    *reinterpret_cast<bf16x8*>(&VTs[0][vrow + 16 * i][vc8]) = vr[i];
  }
  __syncthreads();

  for (int t = 0; t < T; ++t) {
    const int p = t & 1;
    const bool more = (t + 1 < T);

    if (t == ntA - 1) {  // prefetch item-B Q fragments (hidden under tile work)
      int qgB = qtB * 128 + wid * 32 + l31;
#pragma unroll
      for (int ds = 0; ds < 4; ++ds)
        qbB[ds] = scale8(*reinterpret_cast<const bf16x8*>(&Q[qgB * 64 + ds * 16 + h * 8]), sc);
    }
    if (t == ntA) {  // item switch: finish A, start B
      store_out();
      o0 = {}; o1 = {};
      l_run = 0.f;
      qw = qtB * 128 + wid * 32;
      qglob = qw + l31;
#pragma unroll
      for (int ds = 0; ds < 4; ++ds) qb[ds] = qbB[ds];
    }
    const int kv0 = (t < ntA) ? t * 128 : (t - ntA) * 128;
    const bool diag = (t == ntA - 1) || (t == T - 1);  // item's last tile

    if (more) {  // issue next-tile global loads early (T14); kv wraps at ntA
      const int nkv = (t + 1 < ntA) ? (t + 1) * 128 : (t + 1 - ntA) * 128;
#pragma unroll
      for (int i = 0; i < 4; ++i) {
        kr[i] = *reinterpret_cast<const bf16x8*>(&Q[(nkv + krow + 32 * i) * 64 + kc8]);
        vr[i] = *reinterpret_cast<const bf16x8*>(&VT[(vrow + 16 * i) * 2048 + nkv + vc8]);
      }
    }

    // S^T*sc = K (Q*sc)^T: 4 chains x 4 k-steps. D: col=q=lane&31, row=key.
    f32x16 st[4] = {{}, {}, {}, {}};
    __builtin_amdgcn_s_setprio(1);
#pragma unroll
    for (int ds = 0; ds < 4; ++ds) {
#pragma unroll
      for (int c = 0; c < 4; ++c) {
        bf16x8 ka = *reinterpret_cast<const bf16x8*>(&Ks[p][32 * c + l31][ds * 16 + h * 8]);
        st[c] = MFMA32(ka, qb[ds], st[c]);
      }
    }
    __builtin_amdgcn_s_setprio(0);

    if (diag) {  // causal mask, only on the item's last tile
#pragma unroll
      for (int c = 0; c < 4; ++c)
#pragma unroll
        for (int r = 0; r < 16; ++r) {
          int key = kv0 + 32 * c + (r & 3) + 8 * (r >> 2) + 4 * h;
          if (key > qglob) st[c][r] = -1e30f;
        }
    }

    float ls = 0.f;
    // exp2 first half (st[0],st[1]) — feeds PV ks=0..3
#pragma unroll
    for (int c = 0; c < 2; ++c)
#pragma unroll
      for (int r = 0; r < 16; ++r) {
        float pv = __builtin_amdgcn_exp2f(st[c][r]);
        st[c][r] = pv;
        ls += pv;
      }

    // PV first half: ks=0..3 (uses st[0],st[1])
    __builtin_amdgcn_s_setprio(1);
#pragma unroll
    for (int ks = 0; ks < 4; ++ks) {
      const int cc = ks >> 1, b8 = (ks & 1) * 8;
      unsigned a0 = cvtpk(st[cc][b8 + 0], st[cc][b8 + 1]);
      unsigned a1 = cvtpk(st[cc][b8 + 2], st[cc][b8 + 3]);
      unsigned b0 = cvtpk(st[cc][b8 + 4], st[cc][b8 + 5]);
      unsigned b1 = cvtpk(st[cc][b8 + 6], st[cc][b8 + 7]);
      u32x2 r0 = __builtin_amdgcn_permlane32_swap(a0, b0, false, false);
      u32x2 r1 = __builtin_amdgcn_permlane32_swap(a1, b1, false, false);
      union { unsigned w[4]; bf16x8 v; } pb;
      pb.w[0] = r0.x; pb.w[1] = r1.x; pb.w[2] = r0.y; pb.w[3] = r1.y;
      bf16x8 va0 = *reinterpret_cast<const bf16x8*>(&VTs[p][l31][ks * 16 + h * 8]);
      bf16x8 va1 = *reinterpret_cast<const bf16x8*>(&VTs[p][32 + l31][ks * 16 + h * 8]);
      o0 = MFMA32(va0, pb.v, o0);
      o1 = MFMA32(va1, pb.v, o1);
    }
    __builtin_amdgcn_s_setprio(0);

    if (more) {  // staging writes drain under exp2/PV below; barrier is cheap
#pragma unroll
      for (int i = 0; i < 4; ++i) {
        *reinterpret_cast<bf16x8*>(&Ks[p ^ 1][krow + 32 * i][kc8]) = kr[i];
        *reinterpret_cast<bf16x8*>(&VTs[p ^ 1][vrow + 16 * i][vc8]) = vr[i];
      }
    }

    // exp2 second half (st[2],st[3])
#pragma unroll
    for (int c = 2; c < 4; ++c)
#pragma unroll
      for (int r = 0; r < 16; ++r) {
        float pv = __builtin_amdgcn_exp2f(st[c][r]);
        st[c][r] = pv;
        ls += pv;
      }
    l_run += ls;

    // PV second half: ks=4..7 (uses st[2],st[3])
    __builtin_amdgcn_s_setprio(1);
#pragma unroll
    for (int ks = 4; ks < 8; ++ks) {
      const int cc = ks >> 1, b8 = (ks & 1) * 8;
      unsigned a0 = cvtpk(st[cc][b8 + 0], st[cc][b8 + 1]);
      unsigned a1 = cvtpk(st[cc][b8 + 2], st[cc][b8 + 3]);
      unsigned b0 = cvtpk(st[cc][b8 + 4], st[cc][b8 + 5]);
      unsigned b1 = cvtpk(st[cc][b8 + 6], st[cc][b8 + 7]);
      u32x2 r0 = __builtin_amdgcn_permlane32_swap(a0, b0, false, false);
      u32x2 r1 = __builtin_amdgcn_permlane32_swap(a1, b1, false, false);
      union { unsigned w[4]; bf16x8 v; } pb;
      pb.w[0] = r0.x; pb.w[1] = r1.x; pb.w[2] = r0.y; pb.w[3] = r1.y;
      bf16x8 va0 = *reinterpret_cast<const bf16x8*>(&VTs[p][l31][ks * 16 + h * 8]);
      bf16x8 va1 = *reinterpret_cast<const bf16x8*>(&VTs[p][32 + l31][ks * 16 + h * 8]);
      o0 = MFMA32(va0, pb.v, o0);
      o1 = MFMA32(va1, pb.v, o1);
    }
    __builtin_amdgcn_s_setprio(0);

    if (more) __syncthreads();
  }

  store_out();  // item B epilogue
}

extern "C" void kernel_launch(void* const* d_in, const int* in_sizes, int n_in,
                              void* d_out, int out_size, void* d_ws, size_t ws_size,
                              hipStream_t stream) {
  const float* x = (const float*)d_in[0];
  const float* w = (const float*)d_in[1];
  float* out = (float*)d_out;
  ushort* qb = (ushort*)d_ws;
  ushort* qTb = qb + 4 * 16 * 2048 * 64;
  qproj_kernel<<<dim3(64, 8), 256, 0, stream>>>(x, w, qb, qTb);
  attn_kernel<<<512, 256, 0, stream>>>(qb, qTb, out);
}